// Round 1
// baseline (1480.192 us; speedup 1.0000x reference)
//
#include <hip/hip_runtime.h>
#include <hip/hip_bf16.h>

// 6-layer MLP: (Linear -> SiLU) x5 -> Linear.  N = 2,097,152 rows, fp32.
// One thread per row. Activations fully unrolled in VGPRs; weights are
// wave-uniform -> scalar loads (s_load) broadcast into v_fmac_f32.

#define HIDDEN 64

__device__ __forceinline__ float silu(float a) {
    // a * sigmoid(a) = a / (1 + exp(-a))
    return a / (1.0f + __expf(-a));
}

__global__ __launch_bounds__(256) void mlp6_kernel(
    const float* __restrict__ x,
    const float* __restrict__ W0, const float* __restrict__ b0,
    const float* __restrict__ W1, const float* __restrict__ b1,
    const float* __restrict__ W2, const float* __restrict__ b2,
    const float* __restrict__ W3, const float* __restrict__ b3,
    const float* __restrict__ W4, const float* __restrict__ b4,
    const float* __restrict__ Wout, const float* __restrict__ bout,
    float* __restrict__ out, int n)
{
    int i = blockIdx.x * blockDim.x + threadIdx.x;
    if (i >= n) return;

    float xv = x[i];

    float h[HIDDEN];
    float h2[HIDDEN];

    // Layer 0: 1 -> 64, SiLU
#pragma unroll
    for (int j = 0; j < HIDDEN; ++j) {
        float a = fmaf(xv, W0[j], b0[j]);
        h[j] = silu(a);
    }

    // Hidden layers 1..4: 64 -> 64, SiLU.  W is [out=64, in=64] row-major.
#define LAYER(HIN, HOUT, W, B)                                   \
    {                                                            \
        _Pragma("unroll")                                        \
        for (int j = 0; j < HIDDEN; ++j) {                       \
            float acc = (B)[j];                                  \
            _Pragma("unroll")                                    \
            for (int k = 0; k < HIDDEN; ++k)                     \
                acc = fmaf((HIN)[k], (W)[j * HIDDEN + k], acc);  \
            (HOUT)[j] = silu(acc);                               \
        }                                                        \
    }

    LAYER(h, h2, W1, b1);
    LAYER(h2, h, W2, b2);
    LAYER(h, h2, W3, b3);
    LAYER(h2, h, W4, b4);
#undef LAYER

    // Output layer: 64 -> 1, no activation
    float acc = bout[0];
#pragma unroll
    for (int k = 0; k < HIDDEN; ++k)
        acc = fmaf(h[k], Wout[k], acc);

    out[i] = acc;
}

extern "C" void kernel_launch(void* const* d_in, const int* in_sizes, int n_in,
                              void* d_out, int out_size, void* d_ws, size_t ws_size,
                              hipStream_t stream) {
    const float* x    = (const float*)d_in[0];
    const float* W0   = (const float*)d_in[1];
    const float* b0   = (const float*)d_in[2];
    const float* W1   = (const float*)d_in[3];
    const float* b1   = (const float*)d_in[4];
    const float* W2   = (const float*)d_in[5];
    const float* b2   = (const float*)d_in[6];
    const float* W3   = (const float*)d_in[7];
    const float* b3   = (const float*)d_in[8];
    const float* W4   = (const float*)d_in[9];
    const float* b4   = (const float*)d_in[10];
    const float* Wout = (const float*)d_in[11];
    const float* bout = (const float*)d_in[12];
    float* out = (float*)d_out;

    int n = in_sizes[0];  // 2,097,152
    int block = 256;
    int grid = (n + block - 1) / block;
    mlp6_kernel<<<grid, block, 0, stream>>>(x, W0, b0, W1, b1, W2, b2, W3, b3,
                                            W4, b4, Wout, bout, out, n);
}

// Round 3
// 364.985 us; speedup vs baseline: 4.0555x; 4.0555x over previous
//
#include <hip/hip_runtime.h>

// 6-layer MLP (1->64, 4x 64->64, 64->1), N=2,097,152 rows, fp32 in/out.
// Strategy: split-bf16 MFMA (hi+lo bf16 pair per fp32 operand, 3 MFMAs per
// product term, fp32 accumulators) on v_mfma_f32_32x32x16_bf16.
// Per wave: 64 batch rows (2 col-tiles of 32). Per block: 4 waves = 256 rows.
// Weights are pre-split and pre-swizzled into A-fragment order by a prep
// kernel (into d_ws), then staged into 64 KB LDS once per block.
//
// Layout algebra (verified C/D map: col=lane&31=batch, row=(r&3)+8(r>>2)+4h):
// D-slot (m,r,h) holds neuron nu = 32m+(r&3)+8(r>>2)+4h. Permuting layers
// 2..4 weight columns by g(k)=k with bits 2<->3 swapped makes the C->B
// transform a pure in-register reinterpretation: B slot (s2,h,t) takes
// acc[m=s2>>1][r=8(s2&1)+4((t>>2)&1)+(t&3)]. No shuffles, no barriers.
//
// ROUND 2 BUG (fixed): prep wrote strides L=8192,s=2048 (shorts) but main
// read L*4096+s*1024 -> miswired weights for all but layer1/s0. Strides are
// now shared #defines used by BOTH kernels.

typedef short short8 __attribute__((ext_vector_type(8)));
typedef float float16 __attribute__((ext_vector_type(16)));

// A-fragment strides in SHORTS: [L][s][m][part][lane][t]
#define T_STRIDE    8
#define LANE_STRIDE (64 * T_STRIDE)          // 512
#define PART_STRIDE (64 * T_STRIDE)          // (lane dim size 64) -> 512
#define M_STRIDE    (2 * PART_STRIDE)        // 1024
#define S_STRIDE    (2 * M_STRIDE)           // 2048
#define L_STRIDE    (4 * S_STRIDE)           // 8192
#define A_TOTAL     (4 * L_STRIDE)           // 32768 shorts = 65536 B

union BFS { __bf16 b; unsigned short u; };
union BF8 { short8 s; __bf16 e[8]; };

__device__ __forceinline__ float silu_f(float a) {
    float e = __expf(-a);                       // v_exp path
    return a * __builtin_amdgcn_rcpf(1.0f + e); // avoid slow exact divide
}

// ---------------- prep kernel: split + swizzle weights into d_ws ----------
// ws layout:
//   [0, 65536)      : A-frags ushort[L=4][s=4][m=2][part=2][lane=64][t=8]
//   [65536, 66560)  : biases  float [L=4][h=2][m=2][r=16]
//   [66560, 66816)  : Wout    float [h=2][m=2][r=16]
__global__ void prep_kernel(const float* __restrict__ W1, const float* __restrict__ W2,
                            const float* __restrict__ W3, const float* __restrict__ W4,
                            const float* __restrict__ b1, const float* __restrict__ b2,
                            const float* __restrict__ b3, const float* __restrict__ b4,
                            const float* __restrict__ Wout,
                            unsigned char* __restrict__ ws)
{
    unsigned short* A = (unsigned short*)ws;
    float* PB = (float*)(ws + 65536);
    float* PW = (float*)(ws + 66560);
    int tid = blockIdx.x * blockDim.x + threadIdx.x;
    int stride = gridDim.x * blockDim.x;

    const float* Ws[4] = {W1, W2, W3, W4};
    const float* bs[4] = {b1, b2, b3, b4};

    // A-fragments: one (L,s,m,lane) group per iteration, 8 t-elements each.
    for (int i = tid; i < 4 * 4 * 2 * 64; i += stride) {
        int L = i >> 9, s = (i >> 7) & 3, m = (i >> 6) & 1, lane = i & 63;
        int h = lane >> 5;
        int n = m * 32 + (lane & 31);           // A row = out-neuron (lane%32 + 32*Mtile)
        const float* W = Ws[L];
        unsigned short* dh = A + L * L_STRIDE + s * S_STRIDE + m * M_STRIDE
                               + 0 * PART_STRIDE + lane * T_STRIDE;
        unsigned short* dl = A + L * L_STRIDE + s * S_STRIDE + m * M_STRIDE
                               + 1 * PART_STRIDE + lane * T_STRIDE;
        for (int t = 0; t < 8; ++t) {
            int k = s * 16 + h * 8 + t;
            // layer 1 (L==0): columns natural (layer0 labels neurons by k).
            // layers 2..4: column = g(k) = k with bits 2 and 3 swapped.
            int col = (L == 0) ? k : ((k & ~12) | ((k & 4) << 1) | ((k & 8) >> 1));
            float val = W[n * 64 + col];
            BFS hb; hb.b = (__bf16)val;
            float hf = (float)hb.b;
            BFS lb; lb.b = (__bf16)(val - hf);
            dh[t] = hb.u;
            dl[t] = lb.u;
        }
    }

    // biases at D-slot order: nu(m,r,h) = 32m + (r&3) + 8*(r>>2) + 4h
    for (int i = tid; i < 4 * 2 * 2 * 16; i += stride) {
        int L = i >> 6, h = (i >> 5) & 1, m = (i >> 4) & 1, r = i & 15;
        int nu = 32 * m + (r & 3) + 8 * (r >> 2) + 4 * h;
        PB[i] = bs[L][nu];
    }
    // Wout at D-slot order
    for (int i = tid; i < 2 * 2 * 16; i += stride) {
        int h = (i >> 5) & 1, m = (i >> 4) & 1, r = i & 15;
        int nu = 32 * m + (r & 3) + 8 * (r >> 2) + 4 * h;
        PW[i] = Wout[nu];
    }
}

// ---------------- main kernel ---------------------------------------------
__global__ __launch_bounds__(256, 2) void mlp_mfma(
    const float* __restrict__ x, const float* __restrict__ W0,
    const float* __restrict__ b0, const float* __restrict__ bout,
    const unsigned char* __restrict__ ws, float* __restrict__ out)
{
    __shared__ unsigned short ldsA[A_TOTAL];  // 64 KB: prepped A-frags, all 4 layers

    const int tid = threadIdx.x;
    // stage prepped weights global -> LDS (once; only barrier in the kernel)
    {
        const int4* src = (const int4*)ws;
        int4* dst = (int4*)ldsA;
#pragma unroll
        for (int i = 0; i < 16; ++i) dst[tid + i * 256] = src[tid + i * 256];
    }
    __syncthreads();

    const float* PB = (const float*)(ws + 65536);
    const float* PW = (const float*)(ws + 66560);

    const int lane = tid & 63;
    const int wv = tid >> 6;
    const int h = lane >> 5;
    const int lr = lane & 31;
    const int rowbase = blockIdx.x * 256 + wv * 64;

    const float xv0 = x[rowbase + lr];
    const float xv1 = x[rowbase + 32 + lr];

    short8 Bhi[2][4], Blo[2][4];

    // ---- layer 0: 1 -> 64, SiLU, produced directly in B-fragment layout.
    // B position (s,h,t) holds neuron k = 16s + 8h + t.
#pragma unroll
    for (int s = 0; s < 4; ++s) {
        float w0t[8], b0t[8];
        *(float4*)&w0t[0] = *(const float4*)(W0 + s * 16 + h * 8);
        *(float4*)&w0t[4] = *(const float4*)(W0 + s * 16 + h * 8 + 4);
        *(float4*)&b0t[0] = *(const float4*)(b0 + s * 16 + h * 8);
        *(float4*)&b0t[4] = *(const float4*)(b0 + s * 16 + h * 8 + 4);
        BF8 h0, l0, h1, l1;
#pragma unroll
        for (int t = 0; t < 8; ++t) {
            float a0 = silu_f(fmaf(xv0, w0t[t], b0t[t]));
            float a1 = silu_f(fmaf(xv1, w0t[t], b0t[t]));
            __bf16 hb0 = (__bf16)a0;
            __bf16 hb1 = (__bf16)a1;
            h0.e[t] = hb0; l0.e[t] = (__bf16)(a0 - (float)hb0);
            h1.e[t] = hb1; l1.e[t] = (__bf16)(a1 - (float)hb1);
        }
        Bhi[0][s] = h0.s; Blo[0][s] = l0.s;
        Bhi[1][s] = h1.s; Blo[1][s] = l1.s;
    }

    // ---- layers 1..4 (weights W1..W4 staged in LDS)
    float16 acc[2][2];
    for (int L = 0; L < 4; ++L) {
        // bias init (D-slot order, same for both col-tiles)
        const float* pb0 = PB + ((L * 2 + h) * 2 + 0) * 16;
        const float* pb1 = PB + ((L * 2 + h) * 2 + 1) * 16;
#pragma unroll
        for (int r = 0; r < 16; ++r) {
            float v0 = pb0[r], v1 = pb1[r];
            acc[0][0][r] = v0; acc[1][0][r] = v0;
            acc[0][1][r] = v1; acc[1][1][r] = v1;
        }

        const unsigned short* aL = ldsA + L * L_STRIDE;
#pragma unroll
        for (int s = 0; s < 4; ++s) {
            const unsigned short* base = aL + s * S_STRIDE;
            short8 ah0 = *(const short8*)(base + 0 * M_STRIDE + 0 * PART_STRIDE + lane * T_STRIDE);
            short8 al0 = *(const short8*)(base + 0 * M_STRIDE + 1 * PART_STRIDE + lane * T_STRIDE);
            short8 ah1 = *(const short8*)(base + 1 * M_STRIDE + 0 * PART_STRIDE + lane * T_STRIDE);
            short8 al1 = *(const short8*)(base + 1 * M_STRIDE + 1 * PART_STRIDE + lane * T_STRIDE);
            // hi*hi
            acc[0][0] = __builtin_amdgcn_mfma_f32_32x32x16_bf16(ah0, Bhi[0][s], acc[0][0], 0, 0, 0);
            acc[0][1] = __builtin_amdgcn_mfma_f32_32x32x16_bf16(ah1, Bhi[0][s], acc[0][1], 0, 0, 0);
            acc[1][0] = __builtin_amdgcn_mfma_f32_32x32x16_bf16(ah0, Bhi[1][s], acc[1][0], 0, 0, 0);
            acc[1][1] = __builtin_amdgcn_mfma_f32_32x32x16_bf16(ah1, Bhi[1][s], acc[1][1], 0, 0, 0);
            // hi*lo
            acc[0][0] = __builtin_amdgcn_mfma_f32_32x32x16_bf16(ah0, Blo[0][s], acc[0][0], 0, 0, 0);
            acc[0][1] = __builtin_amdgcn_mfma_f32_32x32x16_bf16(ah1, Blo[0][s], acc[0][1], 0, 0, 0);
            acc[1][0] = __builtin_amdgcn_mfma_f32_32x32x16_bf16(ah0, Blo[1][s], acc[1][0], 0, 0, 0);
            acc[1][1] = __builtin_amdgcn_mfma_f32_32x32x16_bf16(ah1, Blo[1][s], acc[1][1], 0, 0, 0);
            // lo*hi
            acc[0][0] = __builtin_amdgcn_mfma_f32_32x32x16_bf16(al0, Bhi[0][s], acc[0][0], 0, 0, 0);
            acc[0][1] = __builtin_amdgcn_mfma_f32_32x32x16_bf16(al1, Bhi[0][s], acc[0][1], 0, 0, 0);
            acc[1][0] = __builtin_amdgcn_mfma_f32_32x32x16_bf16(al0, Bhi[1][s], acc[1][0], 0, 0, 0);
            acc[1][1] = __builtin_amdgcn_mfma_f32_32x32x16_bf16(al1, Bhi[1][s], acc[1][1], 0, 0, 0);
        }

        if (L < 3) {
            // SiLU + hi/lo split, in place: B slot (s2,h,t) <- acc[ct][m][r],
            // m = s2>>1, r = (t&3) + 4*((t>>2)&1) + 8*(s2&1).
#pragma unroll
            for (int ct = 0; ct < 2; ++ct) {
#pragma unroll
                for (int s2 = 0; s2 < 4; ++s2) {
                    BF8 bh, bl;
#pragma unroll
                    for (int t = 0; t < 8; ++t) {
                        const int m = s2 >> 1;
                        const int r = (t & 3) + 4 * ((t >> 2) & 1) + 8 * (s2 & 1);
                        float a = silu_f(acc[ct][m][r]);
                        __bf16 hb = (__bf16)a;
                        bh.e[t] = hb;
                        bl.e[t] = (__bf16)(a - (float)hb);
                    }
                    Bhi[ct][s2] = bh.s;
                    Blo[ct][s2] = bl.s;
                }
            }
        } else {
            // ---- output layer: SiLU then dot with prepped Wout, reduce halves
            const float* pw0 = PW + (h * 2 + 0) * 16;
            const float* pw1 = PW + (h * 2 + 1) * 16;
            float dot0 = 0.0f, dot1 = 0.0f;
#pragma unroll
            for (int r = 0; r < 16; ++r) {
                float w0v = pw0[r], w1v = pw1[r];
                dot0 = fmaf(silu_f(acc[0][0][r]), w0v, dot0);
                dot0 = fmaf(silu_f(acc[0][1][r]), w1v, dot0);
                dot1 = fmaf(silu_f(acc[1][0][r]), w0v, dot1);
                dot1 = fmaf(silu_f(acc[1][1][r]), w1v, dot1);
            }
            dot0 += __shfl_xor(dot0, 32);
            dot1 += __shfl_xor(dot1, 32);
            float bo = bout[0];
            if (h == 0) {
                out[rowbase + lr] = dot0 + bo;
                out[rowbase + 32 + lr] = dot1 + bo;
            }
        }
    }
}

extern "C" void kernel_launch(void* const* d_in, const int* in_sizes, int n_in,
                              void* d_out, int out_size, void* d_ws, size_t ws_size,
                              hipStream_t stream) {
    const float* x    = (const float*)d_in[0];
    const float* W0   = (const float*)d_in[1];
    const float* b0   = (const float*)d_in[2];
    const float* W1   = (const float*)d_in[3];
    const float* b1   = (const float*)d_in[4];
    const float* W2   = (const float*)d_in[5];
    const float* b2   = (const float*)d_in[6];
    const float* W3   = (const float*)d_in[7];
    const float* b3   = (const float*)d_in[8];
    const float* W4   = (const float*)d_in[9];
    const float* b4   = (const float*)d_in[10];
    const float* Wout = (const float*)d_in[11];
    const float* bout = (const float*)d_in[12];
    float* out = (float*)d_out;

    int n = in_sizes[0];  // 2,097,152 (divisible by 256)

    prep_kernel<<<16, 256, 0, stream>>>(W1, W2, W3, W4, b1, b2, b3, b4, Wout,
                                        (unsigned char*)d_ws);
    mlp_mfma<<<n / 256, 256, 0, stream>>>(x, W0, b0, bout,
                                          (const unsigned char*)d_ws, out);
}